// Round 12
// baseline (185.914 us; speedup 1.0000x reference)
//
#include <hip/hip_runtime.h>
#include <hip/hip_bf16.h>

// Problem constants (fixed by setup_inputs)
#define B   8
#define T   2048
#define C   256      // channels; 64 float4
#define L   32       // query rows / label count
#define DQ  512
#define NW  2017     // T - window_size + 1
#define NK  8        // num_chunks
#define CIC 4        // window/num_chunks
#define WT  32       // w-tile per out block
#define KROWS 44     // S4 rows per k-split out block: w(32) + 4k(12) + 1
#define LT  32       // t-rows per label block

typedef float nfloat4 __attribute__((ext_vector_type(4)));  // native vec for nt-store

// ---------------- Kernel 1: enc1/enc2 = query @ W{1,2} + b{1,2} ----------------
// (byte-identical to R11) c-split, 256 blocks -> 1/CU, b128 LDS broadcasts.
__global__ __launch_bounds__(256) void enc_kernel(
    const float* __restrict__ query, const float* __restrict__ W1,
    const float* __restrict__ b1, const float* __restrict__ W2,
    const float* __restrict__ b2, float* __restrict__ enc1,
    float* __restrict__ enc2) {
  const int lg = blockIdx.x, b = blockIdx.y, cs = blockIdx.z;
  const int tid = threadIdx.x;
  const int tx = tid & 63;    // channel within 64-slice
  const int dq = tid >> 6;    // d-quarter (wave-uniform)
  const int c = cs * 64 + tx;
  __shared__ float4 qs4[4][DQ / 4];        // [j][g] 8 KB
  __shared__ float red[2][4][4][64];       // [e][dq][j][tx] 8 KB

  const float4* q4 = (const float4*)(query + ((size_t)b * L + lg * 4) * DQ);
  for (int i = tid; i < 4 * (DQ / 4); i += 256) {
    const int j = i >> 7, g = i & 127;
    qs4[j][g] = q4[j * (DQ / 4) + g];
  }
  __syncthreads();

  float a1[4] = {0.f, 0.f, 0.f, 0.f};
  float a2[4] = {0.f, 0.f, 0.f, 0.f};
  const int g0 = dq * 32;
#pragma unroll 4
  for (int gg = 0; gg < 32; ++gg) {
    const int g = g0 + gg;
    const float4 q0 = qs4[0][g], q1 = qs4[1][g], q2 = qs4[2][g], q3 = qs4[3][g];
    const float* wp1 = W1 + (size_t)(4 * g) * C + c;
    const float* wp2 = W2 + (size_t)(4 * g) * C + c;
    const float w10 = wp1[0], w11 = wp1[C], w12 = wp1[2 * C], w13 = wp1[3 * C];
    const float w20 = wp2[0], w21 = wp2[C], w22 = wp2[2 * C], w23 = wp2[3 * C];
    a1[0] = fmaf(q0.x, w10, fmaf(q0.y, w11, fmaf(q0.z, w12, fmaf(q0.w, w13, a1[0]))));
    a1[1] = fmaf(q1.x, w10, fmaf(q1.y, w11, fmaf(q1.z, w12, fmaf(q1.w, w13, a1[1]))));
    a1[2] = fmaf(q2.x, w10, fmaf(q2.y, w11, fmaf(q2.z, w12, fmaf(q2.w, w13, a1[2]))));
    a1[3] = fmaf(q3.x, w10, fmaf(q3.y, w11, fmaf(q3.z, w12, fmaf(q3.w, w13, a1[3]))));
    a2[0] = fmaf(q0.x, w20, fmaf(q0.y, w21, fmaf(q0.z, w22, fmaf(q0.w, w23, a2[0]))));
    a2[1] = fmaf(q1.x, w20, fmaf(q1.y, w21, fmaf(q1.z, w22, fmaf(q1.w, w23, a2[1]))));
    a2[2] = fmaf(q2.x, w20, fmaf(q2.y, w21, fmaf(q2.z, w22, fmaf(q2.w, w23, a2[2]))));
    a2[3] = fmaf(q3.x, w20, fmaf(q3.y, w21, fmaf(q3.z, w22, fmaf(q3.w, w23, a2[3]))));
  }
#pragma unroll
  for (int j = 0; j < 4; ++j) {
    red[0][dq][j][tx] = a1[j];
    red[1][dq][j][tx] = a2[j];
  }
  __syncthreads();

  for (int o = tid; o < 512; o += 256) {
    const int e = o >> 8, j = (o >> 6) & 3, t = o & 63;
    const float v = red[e][0][j][t] + red[e][1][j][t] +
                    red[e][2][j][t] + red[e][3][j][t];
    const int cc = cs * 64 + t;
    const size_t off = ((size_t)b * L + lg * 4 + j) * C + cc;
    if (e == 0) enc1[off] = v + b1[cc];
    else        enc2[off] = v + b2[cc];
  }
}

// ---------------- Kernel 2: clip_labels = argmax_l (vis . enc1) ----------------
// (byte-identical to R11)
__global__ __launch_bounds__(256) void label_kernel(
    const float* __restrict__ vis, const float* __restrict__ enc1,
    int* __restrict__ labels) {
  const int b = blockIdx.y;
  const int t0 = blockIdx.x * LT;
  const int tid = threadIdx.x;
  const int l = tid & 31;     // label row
  const int part = tid >> 5;  // 8-way channel split (32 ch each)
  __shared__ float4 raw[LT * (C / 4)];               // 32 KB
  __shared__ alignas(16) float pacc[4][LT][36];      // 18.4 KB

  float4 ef[8];
  {
    const float4* e1p = (const float4*)(enc1 + ((size_t)b * L + l) * C) + part * 8;
#pragma unroll
    for (int j = 0; j < 8; ++j) ef[j] = e1p[j];   // L2-hot
  }
  const float4* vb = (const float4*)(vis + (size_t)b * T * C);
  for (int i = tid; i < LT * (C / 4); i += 256)
    raw[i] = vb[(size_t)(t0 + (i >> 6)) * (C / 4) + (i & 63)];
  __syncthreads();

  for (int t = 0; t < LT; ++t) {
    const float4* vr = &raw[t * (C / 4) + part * 8];
    float a = 0.f;
#pragma unroll
    for (int j = 0; j < 8; ++j) {
      const float4 v = vr[j];
      a = fmaf(v.x, ef[j].x, fmaf(v.y, ef[j].y, fmaf(v.z, ef[j].z, fmaf(v.w, ef[j].w, a))));
    }
    a += __shfl_down(a, 32);                    // part pair sum (deterministic)
    if (!(tid & 32)) pacc[tid >> 6][t][l] = a;  // banks (4t+l)%32 distinct: free
  }
  __syncthreads();

  if (tid < LT) {
    float4 s4[8];
#pragma unroll
    for (int j = 0; j < 8; ++j) s4[j] = make_float4(0.f, 0.f, 0.f, 0.f);
#pragma unroll
    for (int p = 0; p < 4; ++p) {
      const float4* pp = (const float4*)pacc[p][tid];
#pragma unroll
      for (int j = 0; j < 8; ++j) {
        s4[j].x += pp[j].x; s4[j].y += pp[j].y;
        s4[j].z += pp[j].z; s4[j].w += pp[j].w;
      }
    }
    float bv = -INFINITY;
    int bi = 0;
#pragma unroll
    for (int j = 0; j < 8; ++j) {
      if (s4[j].x > bv) { bv = s4[j].x; bi = 4 * j; }
      if (s4[j].y > bv) { bv = s4[j].y; bi = 4 * j + 1; }
      if (s4[j].z > bv) { bv = s4[j].z; bi = 4 * j + 2; }
      if (s4[j].w > bv) { bv = s4[j].w; bi = 4 * j + 3; }
    }
    labels[(size_t)b * T + t0 + tid] = bi;
  }
}

// ---------------- Kernel 3: k-split vote + S4 means + modulated output ----------------
// grid (64 wtiles, 8 b, 2 kh) = 1024 blocks. Block (wtile,b,kh) handles
// k in {4kh..4kh+3}; S4 window = rows [base, base+43], base = w0+16*kh.
// LDS 44 KB + slbl -> 3 blocks/CU (R11 was 60 KB -> 2/CU): finer store-phase
// overlap. Wave wv owns k = 4kh+wv; local S4 idx = w + 4*wv (kh-independent).
__global__ __launch_bounds__(256) void out_kernel(
    const float* __restrict__ vis, const float* __restrict__ enc2,
    const int* __restrict__ labels, float* __restrict__ out) {
  const int b = blockIdx.y;
  const int kh = blockIdx.z;
  const int w0 = blockIdx.x * WT;
  const int base = w0 + 16 * kh;        // first S4 row of this block
  const int tid = threadIdx.x;
  const int lane = tid & 63;
  const int wv = tid >> 6;              // wave id, wave-uniform
  __shared__ float4 S4[KROWS * (C / 4)];  // 44 KB, pre-scaled by 0.25
  __shared__ int slbl[KROWS];

  // Prefetch vote labels (in flight alongside raw loads)
  int l0 = 0, l1 = 0, l2 = 0, l3 = 0;
  if (tid < KROWS) {
    const int* lb = labels + (size_t)b * T;
    const int t = base + tid;
#define LCL(tt) lb[(tt) > (T - 1) ? (T - 1) : (tt)]
    l0 = LCL(t); l1 = LCL(t + 1); l2 = LCL(t + 2); l3 = LCL(t + 3);
#undef LCL
  }

  // Phase 1: 14 independent raw-row loads per wave (11 S4 rows + 3 overlap)
  const float4* vb = (const float4*)(vis + (size_t)b * T * C);
  float4 r[14];
  {
    const int s0 = wv * 11;
#pragma unroll
    for (int j = 0; j < 14; ++j) {
      int t = base + s0 + j;
      t = t > (T - 1) ? (T - 1) : t;    // clamp; clamped rows never used
      r[j] = vb[(size_t)t * (C / 4) + lane];
    }
  }

  // Phase 2: majority vote (tie -> smallest label == argmax of one-hot counts)
  if (tid < KROWS) {
    const int c0 = 1 + (l0 == l1) + (l0 == l2) + (l0 == l3);
    const int c1 = 1 + (l1 == l0) + (l1 == l2) + (l1 == l3);
    const int c2 = 1 + (l2 == l0) + (l2 == l1) + (l2 == l3);
    const int c3 = 1 + (l3 == l0) + (l3 == l1) + (l3 == l2);
    int best = l0, bc = c0;
    if (c1 > bc || (c1 == bc && l1 < best)) { best = l1; bc = c1; }
    if (c2 > bc || (c2 == bc && l2 < best)) { best = l2; bc = c2; }
    if (c3 > bc || (c3 == bc && l3 < best)) { best = l3; bc = c3; }
    slbl[tid] = best;
  }

  // Phase 3: S4[s] = mean4(raw rows s..s+3), 11 rows per wave
  {
    const int s0 = wv * 11;
#pragma unroll
    for (int s = 0; s < 11; ++s) {
      float4 o;
      o.x = (r[s].x + r[s + 1].x + r[s + 2].x + r[s + 3].x) * 0.25f;
      o.y = (r[s].y + r[s + 1].y + r[s + 2].y + r[s + 3].y) * 0.25f;
      o.z = (r[s].z + r[s + 1].z + r[s + 2].z + r[s + 3].z) * 0.25f;
      o.w = (r[s].w + r[s + 1].w + r[s + 2].w + r[s + 3].w) * 0.25f;
      S4[(s0 + s) * (C / 4) + lane] = o;
    }
  }
  __syncthreads();

  // Phase 4: output. Wave wv owns k = 4kh+wv; local s = w + 4*wv.
  const float4* e2b = (const float4*)(enc2 + (size_t)b * L * C);
  nfloat4* outp = (nfloat4*)out;
  const int k = 4 * kh + wv;
  const int wlim = (NW - w0) < WT ? (NW - w0) : WT;
#pragma unroll 4
  for (int w = 0; w < wlim; ++w) {
    const int s = w + 4 * wv;
    const int lb = slbl[s];                       // LDS broadcast
    const float4 e = e2b[lb * (C / 4) + lane];    // L1/L2-hot (32 KB set)
    const float4 sv = S4[s * (C / 4) + lane];
    nfloat4 o;
    o.x = e.x * sv.x; o.y = e.y * sv.y; o.z = e.z * sv.z; o.w = e.w * sv.w;
    __builtin_nontemporal_store(
        o, &outp[(((size_t)b * NW + w0 + w) * NK + k) * (C / 4) + lane]);
  }
}

extern "C" void kernel_launch(void* const* d_in, const int* in_sizes, int n_in,
                              void* d_out, int out_size, void* d_ws, size_t ws_size,
                              hipStream_t stream) {
  const float* vis   = (const float*)d_in[0];
  const float* query = (const float*)d_in[1];
  const float* W1    = (const float*)d_in[2];
  const float* b1    = (const float*)d_in[3];
  const float* W2    = (const float*)d_in[4];
  const float* b2    = (const float*)d_in[5];
  float* out = (float*)d_out;

  // Workspace: enc1 (64K f), enc2 (64K f), labels (16K int) = 576 KB
  float* enc1 = (float*)d_ws;
  float* enc2 = enc1 + (size_t)B * L * C;
  int* labels = (int*)(enc2 + (size_t)B * L * C);

  enc_kernel<<<dim3(8, B, 4), 256, 0, stream>>>(query, W1, b1, W2, b2, enc1, enc2);
  label_kernel<<<dim3(T / LT, B), 256, 0, stream>>>(vis, enc1, labels);
  out_kernel<<<dim3((NW + WT - 1) / WT, B, 2), 256, 0, stream>>>(vis, enc2, labels, out);
}